// Round 3
// baseline (94.647 us; speedup 1.0000x reference)
//
#include <hip/hip_runtime.h>
#include <stdint.h>

#define N1v 1024
#define NNv 2048

// Kernel A: h = relu(x@W1 + b1) -> fp32 d_out;
//           uT[k][n] = (h[n]@W2)[k] + (n<N1 ? b2[k] : 0)  (k-major, fp32, in d_ws)
__global__ __launch_bounds__(256) void node_kernel(
    const float* __restrict__ x,    // [2048,6]
    const float* __restrict__ W1,   // [6,64]
    const float* __restrict__ b1,   // [64]
    const float* __restrict__ W2,   // [64,64]
    const float* __restrict__ b2,   // [64]
    float* __restrict__ h_out,      // [2048,64]
    float* __restrict__ uT)         // [64][2048]
{
    __shared__ float hs[4][64];
    __shared__ float w2s[64 * 64];   // [m][k]
    const int t  = threadIdx.x;
    const int nl = t >> 6;          // 0..3 (== wave id)
    const int k  = t & 63;
    const int n  = blockIdx.x * 4 + nl;

    // stage W2 -> LDS (coalesced float4, 4 per thread)
    {
        const float4* w2p = (const float4*)W2;
        float4* w2d = (float4*)w2s;
        #pragma unroll
        for (int q = 0; q < 4; ++q) {
            int idx = q * 256 + t;
            w2d[idx] = w2p[idx];
        }
    }

    // phase 1: h row (x row broadcast across the 64 lanes of this node)
    const float2* xp = (const float2*)x;   // 3 float2 per node row
    float2 x0 = xp[n * 3 + 0], x1 = xp[n * 3 + 1], x2 = xp[n * 3 + 2];
    float xv[6] = { x0.x, x0.y, x1.x, x1.y, x2.x, x2.y };
    float acc = b1[k];
    #pragma unroll
    for (int d = 0; d < 6; ++d) acc += xv[d] * W1[d * 64 + k];
    float h = fmaxf(acc, 0.0f);
    h_out[n * 64 + k] = h;           // coalesced
    hs[nl][k] = h;
    __syncthreads();

    // phase 2: u = h @ W2 (+ b2 for src-frame nodes)
    float acc2 = (n < N1v) ? b2[k] : 0.0f;
    #pragma unroll 8
    for (int m = 0; m < 64; ++m)
        acc2 += hs[nl][m] * w2s[m * 64 + k];   // hs broadcast; w2s 2-way (free)
    uT[k * NNv + n] = acc2;
}

// Kernel B: scores[i][j][c] = relu(uS[i]-uD[j]) @ W3 + b3
// block tile: 32 i x 64 j; thread tile: 2 i x 4 j (8 edges)
__global__ __launch_bounds__(256) void edge_kernel(
    const float* __restrict__ uT,   // [64][2048] (d_ws)
    const float* __restrict__ W3,   // [64,3]
    const float* __restrict__ b3,   // [3]
    float* __restrict__ out_s)      // [1024,1024,3]
{
    __shared__ float uS_l[64 * 32];   // [k][ii]
    __shared__ float uD_l[64 * 64];   // [k][jj]
    __shared__ float w3s[64 * 4];     // [k][c], padded to 4

    const int t  = threadIdx.x;
    const int i0 = blockIdx.x * 32;
    const int j0 = blockIdx.y * 64;

    // stage uS: 64k x 32i = 512 float4 (coalesced from k-major uT)
    #pragma unroll
    for (int p = 0; p < 2; ++p) {
        int idx = p * 256 + t;                 // [0,512)
        int kk = idx >> 3;
        int i4 = (idx & 7) << 2;
        *(float4*)&uS_l[kk * 32 + i4] =
            *(const float4*)&uT[kk * NNv + i0 + i4];
    }
    // stage uD: 64k x 64j = 1024 float4
    #pragma unroll
    for (int p = 0; p < 4; ++p) {
        int idx = p * 256 + t;                 // [0,1024)
        int kk = idx >> 4;
        int j4 = (idx & 15) << 2;
        *(float4*)&uD_l[kk * 64 + j4] =
            *(const float4*)&uT[kk * NNv + N1v + j0 + j4];
    }
    if (t < 64) {
        w3s[t * 4 + 0] = W3[t * 3 + 0];
        w3s[t * 4 + 1] = W3[t * 3 + 1];
        w3s[t * 4 + 2] = W3[t * 3 + 2];
        w3s[t * 4 + 3] = 0.0f;
    }
    const float b3v0 = b3[0], b3v1 = b3[1], b3v2 = b3[2];
    __syncthreads();

    const int tx = t & 15;    // j group (4 j's)
    const int ty = t >> 4;    // i group (2 i's)

    float acc[2][4][3];
    #pragma unroll
    for (int a = 0; a < 2; ++a)
        #pragma unroll
        for (int b = 0; b < 4; ++b) {
            acc[a][b][0] = b3v0; acc[a][b][1] = b3v1; acc[a][b][2] = b3v2;
        }

    #pragma unroll 8
    for (int k = 0; k < 64; ++k) {
        float2 us = *(const float2*)&uS_l[k * 32 + ty * 2];   // 4 addrs/wave, broadcast
        float4 ud = *(const float4*)&uD_l[k * 64 + tx * 4];   // 2-way, free
        float4 w3 = *(const float4*)&w3s[k * 4];              // broadcast
        float usv[2] = { us.x, us.y };
        float udv[4] = { ud.x, ud.y, ud.z, ud.w };
        #pragma unroll
        for (int a = 0; a < 2; ++a) {
            #pragma unroll
            for (int b = 0; b < 4; ++b) {
                float dd = fmaxf(usv[a] - udv[b], 0.0f);
                acc[a][b][0] += dd * w3.x;
                acc[a][b][1] += dd * w3.y;
                acc[a][b][2] += dd * w3.z;
            }
        }
    }

    // epilogue: per i-row, 4 j x 3 ch = 12 floats = 3 aligned float4 stores
    #pragma unroll
    for (int a = 0; a < 2; ++a) {
        int i = i0 + ty * 2 + a;
        int j = j0 + tx * 4;
        float4* p = (float4*)(out_s + ((size_t)i * 1024 + j) * 3);
        p[0] = make_float4(acc[a][0][0], acc[a][0][1], acc[a][0][2], acc[a][1][0]);
        p[1] = make_float4(acc[a][1][1], acc[a][1][2], acc[a][2][0], acc[a][2][1]);
        p[2] = make_float4(acc[a][2][2], acc[a][3][0], acc[a][3][1], acc[a][3][2]);
    }
}

extern "C" void kernel_launch(void* const* d_in, const int* in_sizes, int n_in,
                              void* d_out, int out_size, void* d_ws, size_t ws_size,
                              hipStream_t stream) {
    const float* x  = (const float*)d_in[0];
    const float* W1 = (const float*)d_in[1];
    const float* b1 = (const float*)d_in[2];
    const float* W2 = (const float*)d_in[3];
    const float* b2 = (const float*)d_in[4];
    const float* W3 = (const float*)d_in[5];
    const float* b3 = (const float*)d_in[6];
    // d_in[7] edge_index (dense bipartite by construction: src=e/N2, dst=N1+e%N2)
    // d_in[8]/d_in[9] = node_t / node_t1 (1024/1024)

    float* h_out = (float*)d_out;                  // [2048,64]
    float* s_out = h_out + (size_t)NNv * 64;       // [1024,1024,3]
    float* uT    = (float*)d_ws;                   // 64*2048*4 = 512 KB

    hipLaunchKernelGGL(node_kernel, dim3(512), dim3(256), 0, stream,
                       x, W1, b1, W2, b2, h_out, uT);
    hipLaunchKernelGGL(edge_kernel, dim3(32, 16), dim3(256), 0, stream,
                       uT, W3, b3, s_out);
}

// Round 4
// 92.402 us; speedup vs baseline: 1.0243x; 1.0243x over previous
//
#include <hip/hip_runtime.h>
#include <stdint.h>

#define N1v 1024
#define NNv 2048

typedef float v2f __attribute__((ext_vector_type(2)));

// Kernel A: h = relu(x@W1 + b1) -> fp32 d_out;
//           uT[k][n] = (h[n]@W2)[k] + (n<N1 ? b2[k] : 0)  (k-major fp32 in d_ws)
// 16 nodes/block (grid 128): 4x fewer W2 stagings than 4 nodes/block.
__global__ __launch_bounds__(256) void node_kernel(
    const float* __restrict__ x,    // [2048,6]
    const float* __restrict__ W1,   // [6,64]
    const float* __restrict__ b1,   // [64]
    const float* __restrict__ W2,   // [64,64]
    const float* __restrict__ b2,   // [64]
    float* __restrict__ h_out,      // [2048,64]
    float* __restrict__ uT)         // [64][2048]
{
    __shared__ float hs[16][64];
    __shared__ float w2s[64 * 64];   // [m][k]
    const int t  = threadIdx.x;
    const int nl = t >> 6;          // wave id 0..3
    const int k  = t & 63;
    const int base = blockIdx.x * 16;

    // stage W2 -> LDS (coalesced float4, 4 per thread)
    {
        const float4* w2p = (const float4*)W2;
        float4* w2d = (float4*)w2s;
        #pragma unroll
        for (int q = 0; q < 4; ++q) w2d[q * 256 + t] = w2p[q * 256 + t];
    }

    // phase 1: 4 nodes per wave; x row broadcast across the wave's 64 lanes
    const float2* xp = (const float2*)x;
    #pragma unroll
    for (int q = 0; q < 4; ++q) {
        int nloc = nl * 4 + q;
        int n = base + nloc;
        float2 x0 = xp[n * 3 + 0], x1 = xp[n * 3 + 1], x2 = xp[n * 3 + 2];
        float xv[6] = { x0.x, x0.y, x1.x, x1.y, x2.x, x2.y };
        float acc = b1[k];
        #pragma unroll
        for (int d = 0; d < 6; ++d) acc += xv[d] * W1[d * 64 + k];
        float h = fmaxf(acc, 0.0f);
        h_out[n * 64 + k] = h;       // coalesced
        hs[nloc][k] = h;             // conflict-free
    }
    __syncthreads();

    // phase 2: u = h @ W2 (+ b2 for src-frame nodes). Block is entirely one frame
    // (16 | 1024), so the b2 predicate is block-uniform.
    const float b2v = (blockIdx.x < 64) ? b2[k] : 0.0f;
    float acc2[4] = { b2v, b2v, b2v, b2v };
    #pragma unroll 4
    for (int m4 = 0; m4 < 16; ++m4) {
        int m = m4 * 4;
        float w0 = w2s[(m + 0) * 64 + k];
        float w1 = w2s[(m + 1) * 64 + k];
        float w2v = w2s[(m + 2) * 64 + k];
        float w3v = w2s[(m + 3) * 64 + k];
        #pragma unroll
        for (int q = 0; q < 4; ++q) {
            float4 hv = *(const float4*)&hs[nl * 4 + q][m];   // broadcast b128
            acc2[q] += hv.x * w0 + hv.y * w1 + hv.z * w2v + hv.w * w3v;
        }
    }
    #pragma unroll
    for (int q = 0; q < 4; ++q)
        uT[k * NNv + base + nl * 4 + q] = acc2[q];   // 512KB total, L2-absorbed
}

// Kernel B: scores[i][j][c] = relu(uS[i]-uD[j]) @ W3 + b3
// block tile: 32 i x 64 j; thread tile: 2 i x 4 j; inner math packed 2-wide
// (ext_vector_type(2) -> v_pk_add/pk_fma on gfx950).
__global__ __launch_bounds__(256) void edge_kernel(
    const float* __restrict__ uT,   // [64][2048] (d_ws)
    const float* __restrict__ W3,   // [64,3]
    const float* __restrict__ b3,   // [3]
    float* __restrict__ out_s)      // [1024,1024,3]
{
    __shared__ float uS_l[64 * 32];   // [k][ii]
    __shared__ float uD_l[64 * 64];   // [k][jj]
    __shared__ float w3s[64 * 4];     // [k][c], padded to 4

    const int t  = threadIdx.x;
    const int i0 = blockIdx.x * 32;
    const int j0 = blockIdx.y * 64;

    #pragma unroll
    for (int p = 0; p < 2; ++p) {     // uS: 512 float4, coalesced
        int idx = p * 256 + t;
        int kk = idx >> 3;
        int i4 = (idx & 7) << 2;
        *(float4*)&uS_l[kk * 32 + i4] = *(const float4*)&uT[kk * NNv + i0 + i4];
    }
    #pragma unroll
    for (int p = 0; p < 4; ++p) {     // uD: 1024 float4
        int idx = p * 256 + t;
        int kk = idx >> 4;
        int j4 = (idx & 15) << 2;
        *(float4*)&uD_l[kk * 64 + j4] = *(const float4*)&uT[kk * NNv + N1v + j0 + j4];
    }
    if (t < 64) {
        w3s[t * 4 + 0] = W3[t * 3 + 0];
        w3s[t * 4 + 1] = W3[t * 3 + 1];
        w3s[t * 4 + 2] = W3[t * 3 + 2];
        w3s[t * 4 + 3] = 0.0f;
    }
    const float b3v0 = b3[0], b3v1 = b3[1], b3v2 = b3[2];
    __syncthreads();

    const int tx = t & 15;    // j group (4 j's)
    const int ty = t >> 4;    // i group (2 i's)

    // accp[a][p][c]: a = i-idx, p = j-pair (x -> j=2p, y -> j=2p+1), c = channel
    v2f accp[2][2][3];
    #pragma unroll
    for (int a = 0; a < 2; ++a)
        #pragma unroll
        for (int p = 0; p < 2; ++p) {
            accp[a][p][0] = (v2f){b3v0, b3v0};
            accp[a][p][1] = (v2f){b3v1, b3v1};
            accp[a][p][2] = (v2f){b3v2, b3v2};
        }
    const v2f vzero = {0.0f, 0.0f};

    #pragma unroll 8
    for (int k = 0; k < 64; ++k) {
        float2 us = *(const float2*)&uS_l[k * 32 + ty * 2];   // broadcast-ish
        float4 ud = *(const float4*)&uD_l[k * 64 + tx * 4];   // 2-way, free
        float4 w3 = *(const float4*)&w3s[k * 4];              // broadcast
        v2f ud01 = {ud.x, ud.y}, ud23 = {ud.z, ud.w};
        v2f w3x = {w3.x, w3.x}, w3y = {w3.y, w3.y}, w3z = {w3.z, w3.z};
        float usv[2] = { us.x, us.y };
        #pragma unroll
        for (int a = 0; a < 2; ++a) {
            v2f usa = {usv[a], usv[a]};
            v2f d01 = __builtin_elementwise_max(usa - ud01, vzero);
            v2f d23 = __builtin_elementwise_max(usa - ud23, vzero);
            accp[a][0][0] += d01 * w3x;
            accp[a][0][1] += d01 * w3y;
            accp[a][0][2] += d01 * w3z;
            accp[a][1][0] += d23 * w3x;
            accp[a][1][1] += d23 * w3y;
            accp[a][1][2] += d23 * w3z;
        }
    }

    // epilogue: per i-row, 4 j x 3 ch = 12 floats = 3 aligned float4 stores
    #pragma unroll
    for (int a = 0; a < 2; ++a) {
        int i = i0 + ty * 2 + a;
        int j = j0 + tx * 4;
        float4* p = (float4*)(out_s + ((size_t)i * 1024 + j) * 3);
        // j0:(c0,c1,c2) j1:(c0,c1,c2) j2:(c0,c1,c2) j3:(c0,c1,c2)
        p[0] = make_float4(accp[a][0][0].x, accp[a][0][1].x, accp[a][0][2].x,
                           accp[a][0][0].y);
        p[1] = make_float4(accp[a][0][1].y, accp[a][0][2].y,
                           accp[a][1][0].x, accp[a][1][1].x);
        p[2] = make_float4(accp[a][1][2].x,
                           accp[a][1][0].y, accp[a][1][1].y, accp[a][1][2].y);
    }
}

extern "C" void kernel_launch(void* const* d_in, const int* in_sizes, int n_in,
                              void* d_out, int out_size, void* d_ws, size_t ws_size,
                              hipStream_t stream) {
    const float* x  = (const float*)d_in[0];
    const float* W1 = (const float*)d_in[1];
    const float* b1 = (const float*)d_in[2];
    const float* W2 = (const float*)d_in[3];
    const float* b2 = (const float*)d_in[4];
    const float* W3 = (const float*)d_in[5];
    const float* b3 = (const float*)d_in[6];
    // d_in[7] edge_index (dense bipartite by construction), d_in[8]/[9] node counts

    float* h_out = (float*)d_out;                  // [2048,64]
    float* s_out = h_out + (size_t)NNv * 64;       // [1024,1024,3]
    float* uT    = (float*)d_ws;                   // 512 KB

    hipLaunchKernelGGL(node_kernel, dim3(128), dim3(256), 0, stream,
                       x, W1, b1, W2, b2, h_out, uT);
    hipLaunchKernelGGL(edge_kernel, dim3(32, 16), dim3(256), 0, stream,
                       uT, W3, b3, s_out);
}